// Round 7
// baseline (2197.420 us; speedup 1.0000x reference)
//
#include <hip/hip_runtime.h>
#include <math.h>

#define N_CH 62
#define NB 128
#define F 32
#define TLEN 128
#define HID 512
#define G3 1536
#define EPER 992
#define NNODE (N_CH * NB)   // 7936
#define ETOT (EPER * NB)    // 126976
#define DIM (N_CH * F)      // 1984
#define MROWS (NB * TLEN)   // 16384
#define GRU_BLOCKS 16

typedef __attribute__((ext_vector_type(8))) short bf16x8;
typedef __attribute__((ext_vector_type(4))) float f32x4;
typedef __attribute__((ext_vector_type(4))) unsigned int u32x4;

__device__ __forceinline__ unsigned short f2bf(float f) {
  unsigned u = __float_as_uint(f);
  unsigned r = u + 0x7fffu + ((u >> 16) & 1u);
  return (unsigned short)(r >> 16);
}
__device__ __forceinline__ float bf2f(unsigned short u) {
  return __uint_as_float(((unsigned)u) << 16);
}
__device__ __forceinline__ float sigmoidf_(float x) { return 1.f / (1.f + __expf(-x)); }

__device__ __forceinline__ void gl_lds16(const void* g, void* l) {
  __builtin_amdgcn_global_load_lds(
      (const __attribute__((address_space(1))) unsigned int*)g,
      (__attribute__((address_space(3))) unsigned int*)l, 16, 0, 0);
}

// pack high halves of 8 tagged words into bf16x8
__device__ __forceinline__ bf16x8 pack_hi(u32x4 lo, u32x4 hi) {
  u32x4 r;
  r[0] = (lo[0] >> 16) | (lo[1] & 0xffff0000u);
  r[1] = (lo[2] >> 16) | (lo[3] & 0xffff0000u);
  r[2] = (hi[0] >> 16) | (hi[1] & 0xffff0000u);
  r[3] = (hi[2] >> 16) | (hi[3] & 0xffff0000u);
  return __builtin_bit_cast(bf16x8, r);
}

// ---------------- graph preprocessing ----------------
__global__ void k_deg(const int* __restrict__ src, const float* __restrict__ w,
                      float* __restrict__ deg) {
  int e = blockIdx.x * 256 + threadIdx.x;
  if (e < ETOT) atomicAdd(&deg[src[e]], w[e]);
}

__global__ void k_wn(const int* __restrict__ src, const int* __restrict__ dst,
                     const float* __restrict__ w, const float* __restrict__ deg,
                     float* __restrict__ wn) {
  int e = blockIdx.x * 256 + threadIdx.x;
  if (e < ETOT) {
    float ds = deg[src[e]], dd = deg[dst[e]];
    float a = ds > 0.f ? rsqrtf(ds) : 0.f;
    float b = dd > 0.f ? rsqrtf(dd) : 0.f;
    wn[e] = -a * w[e] * b;
  }
}

__global__ void k_ldense(const int* __restrict__ src, const int* __restrict__ dst,
                         const float* __restrict__ wn, float* __restrict__ Lf) {
  int e = blockIdx.x * 256 + threadIdx.x;
  if (e < ETOT) {
    int b = e / EPER;
    int s = src[e] - b * N_CH;
    int d = dst[e] - b * N_CH;
    atomicAdd(&Lf[(size_t)b * 4096 + d * 64 + s], wn[e]);
  }
}

__global__ __launch_bounds__(256) void k_m2(const float* __restrict__ Lf,
                                            unsigned short* __restrict__ Lbf,
                                            unsigned short* __restrict__ M2bf) {
  int b = blockIdx.x, tid = threadIdx.x;
  __shared__ float Ls[4096];
  for (int i = tid; i < 4096; i += 256) Ls[i] = Lf[(size_t)b * 4096 + i];
  __syncthreads();
  for (int h = 0; h < 16; h++) {
    int i = h * 256 + tid;
    int d = i >> 6, s = i & 63;
    float m = 0.f;
#pragma unroll 8
    for (int k = 0; k < 64; k++) m += Ls[d * 64 + k] * Ls[k * 64 + s];
    M2bf[(size_t)b * 4096 + i] = f2bf(2.f * m - (d == s ? 1.f : 0.f));
    Lbf[(size_t)b * 4096 + i] = f2bf(Ls[i]);
  }
}

// x [7936][32][128] fp32 -> Xt0 [b][4096 rows=(t*32+f)][64 n] bf16 — coalesced via LDS transpose
__global__ __launch_bounds__(256) void k_xt(const float* __restrict__ x,
                                            unsigned short* __restrict__ Xt0) {
  int b = blockIdx.x >> 5, f = blockIdx.x & 31;
  int tid = threadIdx.x;
  __shared__ unsigned short T[128 * 72];  // [t][72-padded n]
#pragma unroll
  for (int h = 0; h < 8; h++) {
    int idx = h * 256 + tid;        // n = idx>>5 (0..63), tq = idx&31
    int n = idx >> 5, tq = idx & 31;
    if (n < N_CH) {
      float4 v = *(const float4*)&x[(((size_t)(b * N_CH + n)) * F + f) * TLEN + tq * 4];
      T[(tq * 4 + 0) * 72 + n] = f2bf(v.x);
      T[(tq * 4 + 1) * 72 + n] = f2bf(v.y);
      T[(tq * 4 + 2) * 72 + n] = f2bf(v.z);
      T[(tq * 4 + 3) * 72 + n] = f2bf(v.w);
    } else {
      T[(tq * 4 + 0) * 72 + n] = 0; T[(tq * 4 + 1) * 72 + n] = 0;
      T[(tq * 4 + 2) * 72 + n] = 0; T[(tq * 4 + 3) * 72 + n] = 0;
    }
  }
  __syncthreads();
  int t = tid >> 1, half = tid & 1;
  unsigned short* dst = &Xt0[((size_t)b * 4096 + t * 32 + f) * 64 + half * 32];
#pragma unroll
  for (int q = 0; q < 4; q++) {
    uint4 v = *(const uint4*)&T[t * 72 + half * 32 + q * 8];
    *(uint4*)(dst + q * 8) = v;
  }
}

// -------- fused ChebConv layer --------
template <int LAYER>
__global__ __launch_bounds__(256) void k_cheb(const unsigned short* __restrict__ Xt,
                                              const unsigned short* __restrict__ Lbg,
                                              const unsigned short* __restrict__ M2g,
                                              const float* __restrict__ W,
                                              const float* __restrict__ bias,
                                              void* __restrict__ outv) {
  int b = blockIdx.x >> 5, ts = blockIdx.x & 31;
  int tid = threadIdx.x;
  int wid = tid >> 6, lane = tid & 63;
  int lr = lane & 15, lk = lane >> 4;
  __shared__ unsigned short Z0[128 * 64];
  __shared__ unsigned short P1[128 * 64];
  __shared__ unsigned short P2[128 * 64];

  const size_t tile_base = ((size_t)b * 4096 + ts * 128) * 64;

#pragma unroll
  for (int h = 0; h < 4; h++) {
    int p = h * 256 + tid;
    int row = p >> 3, c = (p & 7) ^ (row & 7);
    gl_lds16(Xt + tile_base + (size_t)row * 64 + c * 8,
             &Z0[(h * 256 + wid * 64) * 8]);
  }
  __syncthreads();

  f32x4 acc1[2][4], acc2[2][4];
#pragma unroll
  for (int mt = 0; mt < 2; mt++)
#pragma unroll
    for (int nt = 0; nt < 4; nt++) {
      acc1[mt][nt] = (f32x4){0.f, 0.f, 0.f, 0.f};
      acc2[mt][nt] = (f32x4){0.f, 0.f, 0.f, 0.f};
    }
  const unsigned short* Lbb = Lbg + (size_t)b * 4096;
  const unsigned short* Mbb = M2g + (size_t)b * 4096;
#pragma unroll
  for (int kk = 0; kk < 2; kk++) {
    bf16x8 af[2];
#pragma unroll
    for (int mt = 0; mt < 2; mt++) {
      int row = wid * 32 + mt * 16 + lr;
      af[mt] = *(const bf16x8*)&Z0[row * 64 + ((((kk << 2) + lk) ^ (row & 7)) << 3)];
    }
#pragma unroll
    for (int nt = 0; nt < 4; nt++) {
      int brow = nt * 16 + lr;
      bf16x8 bL = *(const bf16x8*)&Lbb[brow * 64 + kk * 32 + lk * 8];
      bf16x8 bM = *(const bf16x8*)&Mbb[brow * 64 + kk * 32 + lk * 8];
#pragma unroll
      for (int mt = 0; mt < 2; mt++) {
        acc1[mt][nt] = __builtin_amdgcn_mfma_f32_16x16x32_bf16(af[mt], bL, acc1[mt][nt], 0, 0, 0);
        acc2[mt][nt] = __builtin_amdgcn_mfma_f32_16x16x32_bf16(af[mt], bM, acc2[mt][nt], 0, 0, 0);
      }
    }
  }
#pragma unroll
  for (int mt = 0; mt < 2; mt++)
#pragma unroll
    for (int nt = 0; nt < 4; nt++) {
      int n = nt * 16 + lr;
#pragma unroll
      for (int r = 0; r < 4; r++) {
        int row = wid * 32 + mt * 16 + lk * 4 + r;
        int elem = row * 64 + ((((n >> 3) ^ (row & 7)) << 3)) + (n & 7);
        P1[elem] = f2bf(acc1[mt][nt][r]);
        P2[elem] = f2bf(acc2[mt][nt][r]);
      }
    }
  __syncthreads();

  int tl = tid >> 6, n = tid & 63;
  float acc[32];
#pragma unroll
  for (int g = 0; g < 32; g++) acc[g] = bias[g];
#pragma unroll 4
  for (int f = 0; f < 32; f++) {
    int row = tl * 32 + f;
    int elem = row * 64 + ((((n >> 3) ^ (row & 7)) << 3)) + (n & 7);
    float z0 = bf2f(Z0[elem]);
    float p1 = bf2f(P1[elem]);
    float p2 = bf2f(P2[elem]);
#pragma unroll
    for (int g = 0; g < 32; g++) {
      acc[g] += z0 * W[f * 32 + g] + p1 * W[1024 + f * 32 + g] + p2 * W[2048 + f * 32 + g];
    }
  }

  if (LAYER == 1) {
    unsigned short* out = (unsigned short*)outv;
    unsigned short* dst = out + tile_base + (size_t)(tl * 32) * 64 + n;
#pragma unroll
    for (int g = 0; g < 32; g++) {
      float y = acc[g];
      y = y > 0.f ? y : 0.01f * y;
      dst[g * 64] = f2bf(y);
    }
  } else {
    if (n < N_CH) {
      unsigned uu[16];
#pragma unroll
      for (int q = 0; q < 16; q++)
        uu[q] = (unsigned)f2bf(acc[2 * q]) | ((unsigned)f2bf(acc[2 * q + 1]) << 16);
      unsigned short* dst = (unsigned short*)outv +
                            ((size_t)(b * TLEN + ts * 4 + tl)) * DIM + n * F;
#pragma unroll
      for (int q = 0; q < 4; q++)
        *(uint4*)(dst + q * 8) = *(uint4*)&uu[q * 4];
    }
  }
}

__global__ void k_cvt(const float* __restrict__ in, unsigned short* __restrict__ out, int n) {
  int i = (blockIdx.x * 256 + threadIdx.x) * 4;
  if (i < n) {
    float4 v = *(const float4*)&in[i];
    ushort4 o;
    o.x = f2bf(v.x); o.y = f2bf(v.y); o.z = f2bf(v.z); o.w = f2bf(v.w);
    *(ushort4*)&out[i] = o;
  }
}

// ---------- bf16 MFMA GEMM ----------
__global__ __launch_bounds__(256) void k_gemm_mfma(const unsigned short* __restrict__ Aq,
                                                   const unsigned short* __restrict__ Bq,
                                                   const float* __restrict__ bias,
                                                   float* __restrict__ Cmat) {
  __shared__ unsigned short As[4096];
  __shared__ unsigned short Bs[4096];
  int tid = threadIdx.x;
  int wid = tid >> 6, lane = tid & 63;
  int lr = lane & 15, lk = lane >> 4;
  int m0 = blockIdx.x * 128, n0 = blockIdx.y * 128;
  int wm = (wid & 1) * 64, wn = (wid >> 1) * 64;
  f32x4 zero = {0.f, 0.f, 0.f, 0.f};
  f32x4 acc[4][4];
#pragma unroll
  for (int i = 0; i < 4; i++)
#pragma unroll
    for (int j = 0; j < 4; j++) acc[i][j] = zero;

  int s0 = tid, s1 = tid + 256;
  const unsigned short* ga0 = Aq + (size_t)(m0 + (s0 >> 2)) * DIM + (s0 & 3) * 8;
  const unsigned short* ga1 = Aq + (size_t)(m0 + (s1 >> 2)) * DIM + (s1 & 3) * 8;
  const unsigned short* gb0 = Bq + (size_t)(n0 + (s0 >> 2)) * DIM + (s0 & 3) * 8;
  const unsigned short* gb1 = Bq + (size_t)(n0 + (s1 >> 2)) * DIM + (s1 & 3) * 8;

  for (int k0 = 0; k0 < DIM; k0 += 32) {
    gl_lds16(ga0 + k0, &As[wid * 512]);
    gl_lds16(ga1 + k0, &As[(wid + 4) * 512]);
    gl_lds16(gb0 + k0, &Bs[wid * 512]);
    gl_lds16(gb1 + k0, &Bs[(wid + 4) * 512]);
    __syncthreads();
    bf16x8 a[4], b[4];
#pragma unroll
    for (int mi = 0; mi < 4; mi++)
      a[mi] = *(const bf16x8*)&As[(wm + mi * 16 + lr) * 32 + lk * 8];
#pragma unroll
    for (int ni = 0; ni < 4; ni++)
      b[ni] = *(const bf16x8*)&Bs[(wn + ni * 16 + lr) * 32 + lk * 8];
#pragma unroll
    for (int mi = 0; mi < 4; mi++)
#pragma unroll
      for (int ni = 0; ni < 4; ni++)
        acc[mi][ni] = __builtin_amdgcn_mfma_f32_16x16x32_bf16(a[mi], b[ni], acc[mi][ni], 0, 0, 0);
    __syncthreads();
  }

#pragma unroll
  for (int mi = 0; mi < 4; mi++)
#pragma unroll
    for (int ni = 0; ni < 4; ni++) {
      int row = m0 + wm + mi * 16 + lk * 4;
      int col = n0 + wn + ni * 16 + lr;
      float bv = bias[col];
#pragma unroll
      for (int r = 0; r < 4; r++)
        Cmat[(size_t)(row + r) * G3 + col] = acc[mi][ni][r] + bv;
    }
}

// ---------- persistent GRU: self-tagged h exchange, no flags ----------
// h word = (bf16 h << 16) | step_tag.  Consumer's data load IS the poll.
#define LDK(ARR, I, OFF) \
  asm volatile("global_load_dwordx4 %0, %1, off offset:" OFF " sc0 sc1" \
               : "=v"(ARR[I]) : "v"(hp));
#define LD16_0 \
  LDK(st, 0, "0")    LDK(st, 1, "16")   LDK(st, 2, "128")  LDK(st, 3, "144") \
  LDK(st, 4, "256")  LDK(st, 5, "272")  LDK(st, 6, "384")  LDK(st, 7, "400") \
  LDK(st, 8, "512")  LDK(st, 9, "528")  LDK(st, 10, "640") LDK(st, 11, "656") \
  LDK(st, 12, "768") LDK(st, 13, "784") LDK(st, 14, "896") LDK(st, 15, "912")
#define LD16_1 \
  LDK(st, 0, "1024") LDK(st, 1, "1040") LDK(st, 2, "1152") LDK(st, 3, "1168") \
  LDK(st, 4, "1280") LDK(st, 5, "1296") LDK(st, 6, "1408") LDK(st, 7, "1424") \
  LDK(st, 8, "1536") LDK(st, 9, "1552") LDK(st, 10, "1664") LDK(st, 11, "1680") \
  LDK(st, 12, "1792") LDK(st, 13, "1808") LDK(st, 14, "1920") LDK(st, 15, "1936")
#define STW(P, VAL, OFF) \
  asm volatile("global_store_dword %0, %1, off offset:" OFF " sc0 sc1" \
               :: "v"(P), "v"(VAL) : "memory");
#define TAGCHK \
  unsigned diff = 0; \
  _Pragma("unroll") \
  for (int i_ = 0; i_ < 16; i_++) \
    diff |= (st[i_][0] ^ tag) | (st[i_][1] ^ tag) | (st[i_][2] ^ tag) | (st[i_][3] ^ tag);

__global__ __launch_bounds__(512, 1) void k_gru_persistent(
    const float* __restrict__ xg,              // [B*T][1536] fp32
    const unsigned short* __restrict__ Wb,     // [1536][512] bf16
    const float* __restrict__ bhh,
    unsigned* __restrict__ hA,                 // [128][512] u32 tagged, zeroed
    unsigned* __restrict__ hB,                 // zeroed
    float* __restrict__ hf_out) {              // [128][512] fp32 final
  __shared__ unsigned short Wlds[96 * 520];
  int tid = threadIdx.x;
  int wv = tid >> 6, lane = tid & 63;
  int lr = lane & 15, lk = lane >> 4;
  int jh0 = blockIdx.x * 32;
  int mo = wv * 16;

  for (int i = tid; i < 96 * 64; i += 512) {
    int row = i >> 6, chunk = i & 63;
    int g = row >> 5, jj = row & 31;
    bf16x8 v = *(const bf16x8*)&Wb[(size_t)(g * HID + jh0 + jj) * HID + chunk * 8];
    *(bf16x8*)&Wlds[row * 520 + chunk * 8] = v;
  }
  __syncthreads();

  float br[2], bz[2], bn[2];
#pragma unroll
  for (int a = 0; a < 2; a++) {
    int j = jh0 + a * 16 + lr;
    br[a] = bhh[j]; bz[a] = bhh[HID + j]; bn[a] = bhh[2 * HID + j];
  }

  float hm[2][4];
#pragma unroll
  for (int a = 0; a < 2; a++)
#pragma unroll
    for (int r = 0; r < 4; r++) hm[a][r] = 0.f;

  // prologue: xg for t=0
  float xv[2][4][3];
#pragma unroll
  for (int a = 0; a < 2; a++) {
    int j = jh0 + a * 16 + lr;
#pragma unroll
    for (int r = 0; r < 4; r++) {
      size_t xrow = ((size_t)(mo + lk * 4 + r) * TLEN + 0) * G3;
      xv[a][r][0] = xg[xrow + j];
      xv[a][r][1] = xg[xrow + HID + j];
      xv[a][r][2] = xg[xrow + 2 * HID + j];
    }
  }

  for (int t = 0; t < TLEN; t++) {
    const unsigned* hin = (t & 1) ? hB : hA;
    unsigned* hout = (t & 1) ? hA : hB;
    const unsigned* hp = hin + (size_t)(mo + lr) * HID + lk * 8;
    unsigned tag = (unsigned)t;

    u32x4 st[16];
    bf16x8 av0[8];

    // ---- chunk 0: ks 0..7 (poll = data load) ----
    LD16_0;
    for (;;) {
      asm volatile("s_waitcnt vmcnt(0)" ::: "memory");
      __builtin_amdgcn_sched_barrier(0);
      TAGCHK
      if (__all((int)((diff & 0xffffu) == 0))) break;
      LD16_0;
    }
#pragma unroll
    for (int q = 0; q < 8; q++) av0[q] = pack_hi(st[2 * q], st[2 * q + 1]);

    // ---- issue chunk 1 (overlaps chunk-0 MFMA) ----
    LD16_1;

    f32x4 acc[6];
#pragma unroll
    for (int n = 0; n < 6; n++) acc[n] = (f32x4){0.f, 0.f, 0.f, 0.f};
#pragma unroll
    for (int q = 0; q < 8; q++) {
#pragma unroll
      for (int n = 0; n < 6; n++) {
        bf16x8 bv = *(const bf16x8*)&Wlds[((n >> 1) * 32 + (n & 1) * 16 + lr) * 520 + q * 32 + lk * 8];
        acc[n] = __builtin_amdgcn_mfma_f32_16x16x32_bf16(av0[q], bv, acc[n], 0, 0, 0);
      }
    }

    // ---- chunk 1 poll ----
    for (;;) {
      asm volatile("s_waitcnt vmcnt(0)" ::: "memory");
      __builtin_amdgcn_sched_barrier(0);
      TAGCHK
      if (__all((int)((diff & 0xffffu) == 0))) break;
      LD16_1;
    }

    // xg prefetch for t+1 (drains under chunk-1 MFMA / gates / stores)
    float xn[2][4][3];
    {
      int tp = (t + 1 < TLEN) ? t + 1 : t;
#pragma unroll
      for (int a = 0; a < 2; a++) {
        int j = jh0 + a * 16 + lr;
#pragma unroll
        for (int r = 0; r < 4; r++) {
          size_t xrow = ((size_t)(mo + lk * 4 + r) * TLEN + tp) * G3;
          xn[a][r][0] = xg[xrow + j];
          xn[a][r][1] = xg[xrow + HID + j];
          xn[a][r][2] = xg[xrow + 2 * HID + j];
        }
      }
    }

#pragma unroll
    for (int q = 0; q < 8; q++) {
      bf16x8 av = pack_hi(st[2 * q], st[2 * q + 1]);
#pragma unroll
      for (int n = 0; n < 6; n++) {
        bf16x8 bv = *(const bf16x8*)&Wlds[((n >> 1) * 32 + (n & 1) * 16 + lr) * 520 + (8 + q) * 32 + lk * 8];
        acc[n] = __builtin_amdgcn_mfma_f32_16x16x32_bf16(av, bv, acc[n], 0, 0, 0);
      }
    }

    // gates
    unsigned w_[2][4];
#pragma unroll
    for (int a = 0; a < 2; a++) {
#pragma unroll
      for (int r = 0; r < 4; r++) {
        float rr = sigmoidf_(xv[a][r][0] + acc[a][r] + br[a]);
        float zz = sigmoidf_(xv[a][r][1] + acc[2 + a][r] + bz[a]);
        float nn = tanhf(xv[a][r][2] + rr * (acc[4 + a][r] + bn[a]));
        float hnew = (1.f - zz) * nn + zz * hm[a][r];
        hm[a][r] = hnew;
        w_[a][r] = ((unsigned)f2bf(hnew) << 16) | (unsigned)(t + 1);
      }
    }

    if (t < TLEN - 1) {
      unsigned* hop = hout + (size_t)(mo + lk * 4) * HID + jh0 + lr;
      unsigned* hop2 = hop + 2 * HID;
      STW(hop,  w_[0][0], "0")    STW(hop,  w_[0][1], "2048")
      STW(hop2, w_[0][2], "0")    STW(hop2, w_[0][3], "2048")
      STW(hop,  w_[1][0], "64")   STW(hop,  w_[1][1], "2112")
      STW(hop2, w_[1][2], "64")   STW(hop2, w_[1][3], "2112")
    }

#pragma unroll
    for (int a = 0; a < 2; a++)
#pragma unroll
      for (int r = 0; r < 4; r++) {
        xv[a][r][0] = xn[a][r][0];
        xv[a][r][1] = xn[a][r][1];
        xv[a][r][2] = xn[a][r][2];
      }
  }

#pragma unroll
  for (int a = 0; a < 2; a++)
#pragma unroll
    for (int r = 0; r < 4; r++)
      hf_out[(size_t)(mo + lk * 4 + r) * HID + jh0 + a * 16 + lr] = hm[a][r];
}

__global__ void k_final(const float* __restrict__ h, const float* __restrict__ Wlin,
                        const float* __restrict__ blin, float* __restrict__ out) {
  int b = blockIdx.x;
  int tid = threadIdx.x;
  int o = tid >> 6, lane = tid & 63;
  float acc = 0.f;
  for (int k = lane; k < HID; k += 64) acc += h[(size_t)b * HID + k] * Wlin[o * HID + k];
#pragma unroll
  for (int off = 32; off; off >>= 1) acc += __shfl_down(acc, off);
  if (lane == 0) out[b * 4 + o] = acc + blin[o];
}

extern "C" void kernel_launch(void* const* d_in, const int* in_sizes, int n_in,
                              void* d_out, int out_size, void* d_ws, size_t ws_size,
                              hipStream_t stream) {
  const float* x = (const float*)d_in[0];
  const int* eidx = (const int*)d_in[1];
  const float* ew = (const float*)d_in[2];
  const float* Wc1 = (const float*)d_in[4];
  const float* bc1 = (const float*)d_in[5];
  const float* Wc2 = (const float*)d_in[6];
  const float* bc2 = (const float*)d_in[7];
  const float* Wih = (const float*)d_in[8];
  const float* Whh = (const float*)d_in[9];
  const float* bih = (const float*)d_in[10];
  const float* bhh = (const float*)d_in[11];
  const float* Wlin = (const float*)d_in[12];
  const float* blin = (const float*)d_in[13];
  const int* src = eidx;
  const int* dst = eidx + ETOT;

  char* ws = (char*)d_ws;
  unsigned short* Xt0 = (unsigned short*)ws;                  // 67,108,864
  unsigned short* Xt1 = (unsigned short*)(ws + 67108864);     // 67,108,864
  unsigned short* Db  = (unsigned short*)(ws + 134217728);    // 65,011,712
  float* xg = (float*)(ws + 199229440);                       // 100,663,296
  char* S = ws + 299892736;
  float* deg = (float*)S;                                     // 32768
  float* wn = (float*)(S + 32768);                            // 507904
  float* Lf = (float*)(S + 540672);                           // 2097152
  unsigned short* Lb = (unsigned short*)(S + 2637824);        // 1048576
  unsigned short* M2b = (unsigned short*)(S + 3686400);       // 1048576
  unsigned short* Wihb = (unsigned short*)(S + 4734976);      // 6094848
  unsigned short* Whhb = (unsigned short*)(S + 10829824);     // 1572864
  float* hf = (float*)(S + 12402688);                         // 262144
  unsigned* hA32 = (unsigned*)(S + 12664832);                 // 262144
  unsigned* hB32 = (unsigned*)(S + 12926976);                 // 262144

  if (ws_size < 313081856) return;

  hipMemsetAsync(deg, 0, 32768, stream);
  hipMemsetAsync(Lf, 0, 2097152, stream);
  hipMemsetAsync(hA32, 0, 262144, stream);
  hipMemsetAsync(hB32, 0, 262144, stream);

  k_deg<<<ETOT / 256, 256, 0, stream>>>(src, ew, deg);
  k_wn<<<ETOT / 256, 256, 0, stream>>>(src, dst, ew, deg, wn);
  k_ldense<<<ETOT / 256, 256, 0, stream>>>(src, dst, wn, Lf);
  k_m2<<<NB, 256, 0, stream>>>(Lf, Lb, M2b);
  k_xt<<<NB * 32, 256, 0, stream>>>(x, Xt0);

  k_cheb<1><<<NB * 32, 256, 0, stream>>>(Xt0, Lb, M2b, Wc1, bc1, Xt1);
  k_cheb<2><<<NB * 32, 256, 0, stream>>>(Xt1, Lb, M2b, Wc2, bc2, Db);

  k_cvt<<<(G3 * DIM / 4 + 255) / 256, 256, 0, stream>>>(Wih, Wihb, G3 * DIM);
  k_cvt<<<(G3 * HID / 4 + 255) / 256, 256, 0, stream>>>(Whh, Whhb, G3 * HID);

  dim3 gg(MROWS / 128, G3 / 128);
  k_gemm_mfma<<<gg, 256, 0, stream>>>(Db, Wihb, bih, xg);

  k_gru_persistent<<<GRU_BLOCKS, 512, 0, stream>>>(xg, Whhb, bhh, hA32, hB32, hf);

  k_final<<<NB, 256, 0, stream>>>(hf, Wlin, blin, (float*)d_out);
}

// Round 8
// 1764.672 us; speedup vs baseline: 1.2452x; 1.2452x over previous
//
#include <hip/hip_runtime.h>
#include <math.h>

#define N_CH 62
#define NB 128
#define F 32
#define TLEN 128
#define HID 512
#define G3 1536
#define EPER 992
#define NNODE (N_CH * NB)   // 7936
#define ETOT (EPER * NB)    // 126976
#define DIM (N_CH * F)      // 1984
#define MROWS (NB * TLEN)   // 16384
#define GEMM_BLOCKS 192
#define GRU_BLOCKS 16

typedef __attribute__((ext_vector_type(8))) short bf16x8;
typedef __attribute__((ext_vector_type(4))) float f32x4;

__device__ __forceinline__ unsigned short f2bf(float f) {
  unsigned u = __float_as_uint(f);
  unsigned r = u + 0x7fffu + ((u >> 16) & 1u);
  return (unsigned short)(r >> 16);
}
__device__ __forceinline__ float bf2f(unsigned short u) {
  return __uint_as_float(((unsigned)u) << 16);
}
__device__ __forceinline__ float sigmoidf_(float x) { return 1.f / (1.f + __expf(-x)); }

__device__ __forceinline__ void gl_lds16(const void* g, void* l) {
  __builtin_amdgcn_global_load_lds(
      (const __attribute__((address_space(1))) unsigned int*)g,
      (__attribute__((address_space(3))) unsigned int*)l, 16, 0, 0);
}

// ---------------- graph preprocessing ----------------
__global__ void k_deg(const int* __restrict__ src, const float* __restrict__ w,
                      float* __restrict__ deg) {
  int e = blockIdx.x * 256 + threadIdx.x;
  if (e < ETOT) atomicAdd(&deg[src[e]], w[e]);
}

__global__ void k_wn(const int* __restrict__ src, const int* __restrict__ dst,
                     const float* __restrict__ w, const float* __restrict__ deg,
                     float* __restrict__ wn) {
  int e = blockIdx.x * 256 + threadIdx.x;
  if (e < ETOT) {
    float ds = deg[src[e]], dd = deg[dst[e]];
    float a = ds > 0.f ? rsqrtf(ds) : 0.f;
    float b = dd > 0.f ? rsqrtf(dd) : 0.f;
    wn[e] = -a * w[e] * b;
  }
}

__global__ void k_ldense(const int* __restrict__ src, const int* __restrict__ dst,
                         const float* __restrict__ wn, float* __restrict__ Lf) {
  int e = blockIdx.x * 256 + threadIdx.x;
  if (e < ETOT) {
    int b = e / EPER;
    int s = src[e] - b * N_CH;
    int d = dst[e] - b * N_CH;
    atomicAdd(&Lf[(size_t)b * 4096 + d * 64 + s], wn[e]);
  }
}

__global__ __launch_bounds__(256) void k_m2(const float* __restrict__ Lf,
                                            unsigned short* __restrict__ Lbf,
                                            unsigned short* __restrict__ M2bf) {
  int b = blockIdx.x, tid = threadIdx.x;
  __shared__ float Ls[4096];
  for (int i = tid; i < 4096; i += 256) Ls[i] = Lf[(size_t)b * 4096 + i];
  __syncthreads();
  for (int h = 0; h < 16; h++) {
    int i = h * 256 + tid;
    int d = i >> 6, s = i & 63;
    float m = 0.f;
#pragma unroll 8
    for (int k = 0; k < 64; k++) m += Ls[d * 64 + k] * Ls[k * 64 + s];
    M2bf[(size_t)b * 4096 + i] = f2bf(2.f * m - (d == s ? 1.f : 0.f));
    Lbf[(size_t)b * 4096 + i] = f2bf(Ls[i]);
  }
}

// x [7936][32][128] fp32 -> Xt0 [b][4096 rows=(t*32+f)][64 n] bf16 — coalesced via LDS transpose
__global__ __launch_bounds__(256) void k_xt(const float* __restrict__ x,
                                            unsigned short* __restrict__ Xt0) {
  int b = blockIdx.x >> 5, f = blockIdx.x & 31;
  int tid = threadIdx.x;
  __shared__ unsigned short T[128 * 72];
#pragma unroll
  for (int h = 0; h < 8; h++) {
    int idx = h * 256 + tid;
    int n = idx >> 5, tq = idx & 31;
    if (n < N_CH) {
      float4 v = *(const float4*)&x[(((size_t)(b * N_CH + n)) * F + f) * TLEN + tq * 4];
      T[(tq * 4 + 0) * 72 + n] = f2bf(v.x);
      T[(tq * 4 + 1) * 72 + n] = f2bf(v.y);
      T[(tq * 4 + 2) * 72 + n] = f2bf(v.z);
      T[(tq * 4 + 3) * 72 + n] = f2bf(v.w);
    } else {
      T[(tq * 4 + 0) * 72 + n] = 0; T[(tq * 4 + 1) * 72 + n] = 0;
      T[(tq * 4 + 2) * 72 + n] = 0; T[(tq * 4 + 3) * 72 + n] = 0;
    }
  }
  __syncthreads();
  int t = tid >> 1, half = tid & 1;
  unsigned short* dst = &Xt0[((size_t)b * 4096 + t * 32 + f) * 64 + half * 32];
#pragma unroll
  for (int q = 0; q < 4; q++) {
    uint4 v = *(const uint4*)&T[t * 72 + half * 32 + q * 8];
    *(uint4*)(dst + q * 8) = v;
  }
}

// -------- fused ChebConv layer --------
template <int LAYER>
__global__ __launch_bounds__(256) void k_cheb(const unsigned short* __restrict__ Xt,
                                              const unsigned short* __restrict__ Lbg,
                                              const unsigned short* __restrict__ M2g,
                                              const float* __restrict__ W,
                                              const float* __restrict__ bias,
                                              void* __restrict__ outv) {
  int b = blockIdx.x >> 5, ts = blockIdx.x & 31;
  int tid = threadIdx.x;
  int wid = tid >> 6, lane = tid & 63;
  int lr = lane & 15, lk = lane >> 4;
  __shared__ unsigned short Z0[128 * 64];
  __shared__ unsigned short P1[128 * 64];
  __shared__ unsigned short P2[128 * 64];

  const size_t tile_base = ((size_t)b * 4096 + ts * 128) * 64;

#pragma unroll
  for (int h = 0; h < 4; h++) {
    int p = h * 256 + tid;
    int row = p >> 3, c = (p & 7) ^ (row & 7);
    gl_lds16(Xt + tile_base + (size_t)row * 64 + c * 8,
             &Z0[(h * 256 + wid * 64) * 8]);
  }
  __syncthreads();

  f32x4 acc1[2][4], acc2[2][4];
#pragma unroll
  for (int mt = 0; mt < 2; mt++)
#pragma unroll
    for (int nt = 0; nt < 4; nt++) {
      acc1[mt][nt] = (f32x4){0.f, 0.f, 0.f, 0.f};
      acc2[mt][nt] = (f32x4){0.f, 0.f, 0.f, 0.f};
    }
  const unsigned short* Lbb = Lbg + (size_t)b * 4096;
  const unsigned short* Mbb = M2g + (size_t)b * 4096;
#pragma unroll
  for (int kk = 0; kk < 2; kk++) {
    bf16x8 af[2];
#pragma unroll
    for (int mt = 0; mt < 2; mt++) {
      int row = wid * 32 + mt * 16 + lr;
      af[mt] = *(const bf16x8*)&Z0[row * 64 + ((((kk << 2) + lk) ^ (row & 7)) << 3)];
    }
#pragma unroll
    for (int nt = 0; nt < 4; nt++) {
      int brow = nt * 16 + lr;
      bf16x8 bL = *(const bf16x8*)&Lbb[brow * 64 + kk * 32 + lk * 8];
      bf16x8 bM = *(const bf16x8*)&Mbb[brow * 64 + kk * 32 + lk * 8];
#pragma unroll
      for (int mt = 0; mt < 2; mt++) {
        acc1[mt][nt] = __builtin_amdgcn_mfma_f32_16x16x32_bf16(af[mt], bL, acc1[mt][nt], 0, 0, 0);
        acc2[mt][nt] = __builtin_amdgcn_mfma_f32_16x16x32_bf16(af[mt], bM, acc2[mt][nt], 0, 0, 0);
      }
    }
  }
#pragma unroll
  for (int mt = 0; mt < 2; mt++)
#pragma unroll
    for (int nt = 0; nt < 4; nt++) {
      int n = nt * 16 + lr;
#pragma unroll
      for (int r = 0; r < 4; r++) {
        int row = wid * 32 + mt * 16 + lk * 4 + r;
        int elem = row * 64 + ((((n >> 3) ^ (row & 7)) << 3)) + (n & 7);
        P1[elem] = f2bf(acc1[mt][nt][r]);
        P2[elem] = f2bf(acc2[mt][nt][r]);
      }
    }
  __syncthreads();

  int tl = tid >> 6, n = tid & 63;
  float acc[32];
#pragma unroll
  for (int g = 0; g < 32; g++) acc[g] = bias[g];
#pragma unroll 4
  for (int f = 0; f < 32; f++) {
    int row = tl * 32 + f;
    int elem = row * 64 + ((((n >> 3) ^ (row & 7)) << 3)) + (n & 7);
    float z0 = bf2f(Z0[elem]);
    float p1 = bf2f(P1[elem]);
    float p2 = bf2f(P2[elem]);
#pragma unroll
    for (int g = 0; g < 32; g++) {
      acc[g] += z0 * W[f * 32 + g] + p1 * W[1024 + f * 32 + g] + p2 * W[2048 + f * 32 + g];
    }
  }

  if (LAYER == 1) {
    unsigned short* out = (unsigned short*)outv;
    unsigned short* dst = out + tile_base + (size_t)(tl * 32) * 64 + n;
#pragma unroll
    for (int g = 0; g < 32; g++) {
      float y = acc[g];
      y = y > 0.f ? y : 0.01f * y;
      dst[g * 64] = f2bf(y);
    }
  } else {
    // seq layout [t][b][DIM] (for fused GEMM: m = t*NB + b)
    if (n < N_CH) {
      unsigned uu[16];
#pragma unroll
      for (int q = 0; q < 16; q++)
        uu[q] = (unsigned)f2bf(acc[2 * q]) | ((unsigned)f2bf(acc[2 * q + 1]) << 16);
      unsigned short* dst = (unsigned short*)outv +
                            ((size_t)(ts * 4 + tl) * NB + b) * DIM + n * F;
#pragma unroll
      for (int q = 0; q < 4; q++)
        *(uint4*)(dst + q * 8) = *(uint4*)&uu[q * 4];
    }
  }
}

__global__ void k_cvt(const float* __restrict__ in, unsigned short* __restrict__ out, int n) {
  int i = (blockIdx.x * 256 + threadIdx.x) * 4;
  if (i < n) {
    float4 v = *(const float4*)&in[i];
    ushort4 o;
    o.x = f2bf(v.x); o.y = f2bf(v.y); o.z = f2bf(v.z); o.w = f2bf(v.w);
    *(ushort4*)&out[i] = o;
  }
}

// ---------- fused persistent kernel: GEMM (blocks 0..191) + GRU (blocks 192..207) ----------
// coherent single-element access macros (cross-XCD via coherence point)
#define LDH(I, OFFS) \
  asm volatile("global_load_dwordx4 %0, %1, off offset:" OFFS " sc0 sc1" \
               : "=v"(av[I]) : "v"(hin_p));
#define STH(VAL, OFFS) \
  asm volatile("global_store_short %0, %1, off offset:" OFFS " sc0 sc1" \
               :: "v"(hout_p), "v"((unsigned)(VAL)) : "memory");
#define STC(P, VAL) \
  asm volatile("global_store_dword %0, %1, off sc0 sc1" \
               :: "v"(P), "v"(VAL) : "memory");

__global__ __launch_bounds__(512, 1) void k_fused(
    const unsigned short* __restrict__ seq,    // [T][B][DIM] bf16
    const unsigned short* __restrict__ Wihb,   // [1536][DIM] bf16
    const float* __restrict__ bih,
    float* __restrict__ xg,                    // [T][B][1536] fp32 (coherent)
    unsigned int* __restrict__ cnt,            // [128] t-row counters, zeroed
    const unsigned short* __restrict__ Whhb,   // [1536][512] bf16
    const float* __restrict__ bhh,
    unsigned short* __restrict__ hbA,          // [128][512] bf16, zeroed
    unsigned short* __restrict__ hbB,
    float* __restrict__ hf_out,                // [128][512] fp32 final
    unsigned int* __restrict__ flags) {        // 16 x 16 uints, zeroed
  __shared__ unsigned short As[4096];          // GEMM A tile [128][32]
  __shared__ unsigned short Bs[4096];          // GEMM B tile
  __shared__ unsigned short Wlds[96 * 520];    // GRU W slice
  int tid = threadIdx.x;
  int wv = tid >> 6, lane = tid & 63;
  int lr = lane & 15, lk = lane >> 4;

  if (blockIdx.x < GEMM_BLOCKS) {
    // ================= GEMM: xg = seq @ Wih^T + bih =================
    int wm2 = wv & 1, wn4 = wv >> 1;
    for (int s = 0; s < 8; s++) {
      int tile = blockIdx.x + GEMM_BLOCKS * s;     // row-major: early tiles = early t
      int mt = tile / 12, nt = tile % 12;
      int m0 = mt * 128, n0 = nt * 128;
      f32x4 acc[4][2];
#pragma unroll
      for (int i = 0; i < 4; i++)
#pragma unroll
        for (int j = 0; j < 2; j++) acc[i][j] = (f32x4){0.f, 0.f, 0.f, 0.f};

      const unsigned short* ga = seq + (size_t)(m0 + (tid >> 2)) * DIM + (tid & 3) * 8;
      const unsigned short* gb = Wihb + (size_t)(n0 + (tid >> 2)) * DIM + (tid & 3) * 8;
      for (int k0 = 0; k0 < DIM; k0 += 32) {
        __syncthreads();
        gl_lds16(ga + k0, &As[wv * 512]);
        gl_lds16(gb + k0, &Bs[wv * 512]);
        __syncthreads();
        bf16x8 a[4], b[2];
#pragma unroll
        for (int mi = 0; mi < 4; mi++)
          a[mi] = *(const bf16x8*)&As[(wm2 * 64 + mi * 16 + lr) * 32 + lk * 8];
#pragma unroll
        for (int ni = 0; ni < 2; ni++)
          b[ni] = *(const bf16x8*)&Bs[(wn4 * 32 + ni * 16 + lr) * 32 + lk * 8];
#pragma unroll
        for (int mi = 0; mi < 4; mi++)
#pragma unroll
          for (int ni = 0; ni < 2; ni++)
            acc[mi][ni] = __builtin_amdgcn_mfma_f32_16x16x32_bf16(a[mi], b[ni], acc[mi][ni], 0, 0, 0);
      }
      float bv[2];
      bv[0] = bih[n0 + wn4 * 32 + lr];
      bv[1] = bih[n0 + wn4 * 32 + 16 + lr];
#pragma unroll
      for (int mi = 0; mi < 4; mi++)
#pragma unroll
        for (int ni = 0; ni < 2; ni++) {
          int col = n0 + wn4 * 32 + ni * 16 + lr;
          int row0 = m0 + wm2 * 64 + mi * 16 + lk * 4;
#pragma unroll
          for (int r = 0; r < 4; r++) {
            float v = acc[mi][ni][r] + bv[ni];
            float* p = xg + (size_t)(row0 + r) * G3 + col;
            STC(p, v)
          }
        }
      asm volatile("s_waitcnt vmcnt(0)" ::: "memory");
      __syncthreads();
      if (tid == 0)
        __hip_atomic_fetch_add(&cnt[mt], 1u, __ATOMIC_RELAXED, __HIP_MEMORY_SCOPE_AGENT);
    }
    return;
  }

  // ================= GRU: persistent, flag-synced (R6 protocol) =================
  int jb = blockIdx.x - GEMM_BLOCKS;
  int jh0 = jb * 32;
  int mo = wv * 16;

  for (int i = tid; i < 96 * 64; i += 512) {
    int row = i >> 6, chunk = i & 63;
    int g = row >> 5, jj = row & 31;
    bf16x8 v = *(const bf16x8*)&Whhb[(size_t)(g * HID + jh0 + jj) * HID + chunk * 8];
    *(bf16x8*)&Wlds[row * 520 + chunk * 8] = v;
  }
  __syncthreads();

  float br[2], bz[2], bn[2];
#pragma unroll
  for (int a = 0; a < 2; a++) {
    int j = jh0 + a * 16 + lr;
    br[a] = bhh[j]; bz[a] = bhh[HID + j]; bn[a] = bhh[2 * HID + j];
  }

  float hm[2][4];
#pragma unroll
  for (int a = 0; a < 2; a++)
#pragma unroll
    for (int r = 0; r < 4; r++) hm[a][r] = 0.f;

  // prologue: wait for xg t-row 0, then load
  while (__hip_atomic_load(&cnt[0], __ATOMIC_RELAXED, __HIP_MEMORY_SCOPE_AGENT) < 12u)
    __builtin_amdgcn_s_sleep(1);
  float xv[2][4][3];
#pragma unroll
  for (int a = 0; a < 2; a++) {
    int j = jh0 + a * 16 + lr;
#pragma unroll
    for (int r = 0; r < 4; r++) {
      size_t xrow = (size_t)(mo + lk * 4 + r) * G3;   // t=0
      xv[a][r][0] = xg[xrow + j];
      xv[a][r][1] = xg[xrow + HID + j];
      xv[a][r][2] = xg[xrow + 2 * HID + j];
    }
  }

  int fidx = (lane & 15) * 16;

  for (int t = 0; t < TLEN; t++) {
    const unsigned short* hin = (t & 1) ? hbB : hbA;
    unsigned short* hout = (t & 1) ? hbA : hbB;
    const unsigned short* hin_p = hin + (size_t)(mo + lr) * HID + lk * 8;
    unsigned short* hout_p = hout + (size_t)(mo + lk * 4) * HID + jh0 + lr;

    // A) coherent h loads
    bf16x8 av[16];
    LDH(0, "0")    LDH(1, "64")   LDH(2, "128")  LDH(3, "192")
    LDH(4, "256")  LDH(5, "320")  LDH(6, "384")  LDH(7, "448")
    LDH(8, "512")  LDH(9, "576")  LDH(10, "640") LDH(11, "704")
    LDH(12, "768") LDH(13, "832") LDH(14, "896") LDH(15, "960")
    asm volatile("s_waitcnt vmcnt(0)" ::: "memory");
    __builtin_amdgcn_sched_barrier(0);

    // B) MFMA: hg = h @ Whh_slice^T
    f32x4 acc[6];
#pragma unroll
    for (int n = 0; n < 6; n++) acc[n] = (f32x4){0.f, 0.f, 0.f, 0.f};
#pragma unroll
    for (int ks = 0; ks < 16; ks++) {
#pragma unroll
      for (int n = 0; n < 6; n++) {
        bf16x8 bv = *(const bf16x8*)&Wlds[((n >> 1) * 32 + (n & 1) * 16 + lr) * 520 + ks * 32 + lk * 8];
        acc[n] = __builtin_amdgcn_mfma_f32_16x16x32_bf16(av[ks], bv, acc[n], 0, 0, 0);
      }
    }

    // C) gates
    unsigned hv[2][4];
#pragma unroll
    for (int a = 0; a < 2; a++) {
#pragma unroll
      for (int r = 0; r < 4; r++) {
        float rr = sigmoidf_(xv[a][r][0] + acc[a][r] + br[a]);
        float zz = sigmoidf_(xv[a][r][1] + acc[2 + a][r] + bz[a]);
        float nn = tanhf(xv[a][r][2] + rr * (acc[4 + a][r] + bn[a]));
        float hnew = (1.f - zz) * nn + zz * hm[a][r];
        hm[a][r] = hnew;
        hv[a][r] = f2bf(hnew);
      }
    }

    // D) coherent h stores
    STH(hv[0][0], "0")    STH(hv[0][1], "1024") STH(hv[0][2], "2048") STH(hv[0][3], "3072")
    STH(hv[1][0], "32")   STH(hv[1][1], "1056") STH(hv[1][2], "2080") STH(hv[1][3], "3104")

    if (t < TLEN - 1) {
      // E) drain, publish flag, gated xg(t+1) prefetch during spin, all-lane poll
      asm volatile("s_waitcnt vmcnt(0)" ::: "memory");
      __syncthreads();
      if (tid == 0)
        __hip_atomic_store(&flags[jb * 16], (unsigned)(t + 1),
                           __ATOMIC_RELAXED, __HIP_MEMORY_SCOPE_AGENT);

      while (__hip_atomic_load(&cnt[t + 1], __ATOMIC_RELAXED, __HIP_MEMORY_SCOPE_AGENT) < 12u)
        __builtin_amdgcn_s_sleep(1);

      float xn[2][4][3];
#pragma unroll
      for (int a = 0; a < 2; a++) {
        int j = jh0 + a * 16 + lr;
#pragma unroll
        for (int r = 0; r < 4; r++) {
          size_t xrow = ((size_t)(t + 1) * NB + mo + lk * 4 + r) * G3;
          xn[a][r][0] = xg[xrow + j];
          xn[a][r][1] = xg[xrow + HID + j];
          xn[a][r][2] = xg[xrow + 2 * HID + j];
        }
      }

      unsigned tgt = (unsigned)(t + 1);
      while (true) {
        unsigned v = __hip_atomic_load(&flags[fidx], __ATOMIC_RELAXED, __HIP_MEMORY_SCOPE_AGENT);
        if (__ballot(v >= tgt) == ~0ull) break;
        __builtin_amdgcn_s_sleep(0);
      }

#pragma unroll
      for (int a = 0; a < 2; a++)
#pragma unroll
        for (int r = 0; r < 4; r++) {
          xv[a][r][0] = xn[a][r][0];
          xv[a][r][1] = xn[a][r][1];
          xv[a][r][2] = xn[a][r][2];
        }
    }
  }

#pragma unroll
  for (int a = 0; a < 2; a++)
#pragma unroll
    for (int r = 0; r < 4; r++)
      hf_out[(size_t)(mo + lk * 4 + r) * HID + jh0 + a * 16 + lr] = hm[a][r];
}

__global__ void k_final(const float* __restrict__ h, const float* __restrict__ Wlin,
                        const float* __restrict__ blin, float* __restrict__ out) {
  int b = blockIdx.x;
  int tid = threadIdx.x;
  int o = tid >> 6, lane = tid & 63;
  float acc = 0.f;
  for (int k = lane; k < HID; k += 64) acc += h[(size_t)b * HID + k] * Wlin[o * HID + k];
#pragma unroll
  for (int off = 32; off; off >>= 1) acc += __shfl_down(acc, off);
  if (lane == 0) out[b * 4 + o] = acc + blin[o];
}

extern "C" void kernel_launch(void* const* d_in, const int* in_sizes, int n_in,
                              void* d_out, int out_size, void* d_ws, size_t ws_size,
                              hipStream_t stream) {
  const float* x = (const float*)d_in[0];
  const int* eidx = (const int*)d_in[1];
  const float* ew = (const float*)d_in[2];
  const float* Wc1 = (const float*)d_in[4];
  const float* bc1 = (const float*)d_in[5];
  const float* Wc2 = (const float*)d_in[6];
  const float* bc2 = (const float*)d_in[7];
  const float* Wih = (const float*)d_in[8];
  const float* Whh = (const float*)d_in[9];
  const float* bih = (const float*)d_in[10];
  const float* bhh = (const float*)d_in[11];
  const float* Wlin = (const float*)d_in[12];
  const float* blin = (const float*)d_in[13];
  const int* src = eidx;
  const int* dst = eidx + ETOT;

  char* ws = (char*)d_ws;
  unsigned short* Xt0 = (unsigned short*)ws;                  // 67,108,864
  unsigned short* Xt1 = (unsigned short*)(ws + 67108864);     // 67,108,864
  unsigned short* Db  = (unsigned short*)(ws + 134217728);    // 65,011,712 (seq [t][b][DIM])
  float* xg = (float*)(ws + 199229440);                       // 100,663,296 ([t][b][G3])
  char* S = ws + 299892736;
  float* deg = (float*)S;                                     // 32768
  float* wn = (float*)(S + 32768);                            // 507904
  float* Lf = (float*)(S + 540672);                           // 2097152
  unsigned short* Lb = (unsigned short*)(S + 2637824);        // 1048576
  unsigned short* M2b = (unsigned short*)(S + 3686400);       // 1048576
  unsigned short* Wihb = (unsigned short*)(S + 4734976);      // 6094848
  unsigned short* Whhb = (unsigned short*)(S + 10829824);     // 1572864
  float* hf = (float*)(S + 12402688);                         // 262144
  unsigned short* hbA = (unsigned short*)(S + 12664832);      // 131072
  unsigned short* hbB = (unsigned short*)(S + 12795904);      // 131072
  unsigned int* flags = (unsigned int*)(S + 12926976);        // 1024
  unsigned int* cnt = (unsigned int*)(S + 12928000);          // 512

  if (ws_size < 312821248) return;

  hipMemsetAsync(deg, 0, 32768, stream);
  hipMemsetAsync(Lf, 0, 2097152, stream);
  hipMemsetAsync(hbA, 0, 131072, stream);
  hipMemsetAsync(flags, 0, 1024, stream);
  hipMemsetAsync(cnt, 0, 512, stream);

  k_deg<<<ETOT / 256, 256, 0, stream>>>(src, ew, deg);
  k_wn<<<ETOT / 256, 256, 0, stream>>>(src, dst, ew, deg, wn);
  k_ldense<<<ETOT / 256, 256, 0, stream>>>(src, dst, wn, Lf);
  k_m2<<<NB, 256, 0, stream>>>(Lf, Lb, M2b);
  k_xt<<<NB * 32, 256, 0, stream>>>(x, Xt0);

  k_cheb<1><<<NB * 32, 256, 0, stream>>>(Xt0, Lb, M2b, Wc1, bc1, Xt1);
  k_cheb<2><<<NB * 32, 256, 0, stream>>>(Xt1, Lb, M2b, Wc2, bc2, Db);

  k_cvt<<<(G3 * DIM / 4 + 255) / 256, 256, 0, stream>>>(Wih, Wihb, G3 * DIM);
  k_cvt<<<(G3 * HID / 4 + 255) / 256, 256, 0, stream>>>(Whh, Whhb, G3 * HID);

  // fused: GEMM (xg = seq @ Wih^T + bih) overlapped with persistent GRU
  k_fused<<<GEMM_BLOCKS + GRU_BLOCKS, 512, 0, stream>>>(
      Db, Wihb, bih, xg, cnt, Whhb, bhh, hbA, hbB, hf, flags);

  k_final<<<NB, 256, 0, stream>>>(hf, Wlin, blin, (float*)d_out);
}